// Round 7
// baseline (325.686 us; speedup 1.0000x reference)
//
#include <hip/hip_runtime.h>
#include <hip/hip_bf16.h>

#define NSRC 65536
#define NDST 8192
#define H 128

// mixing constants: z2sim = 0.34*sim + 0.495*cor@Wcs + 0.165*sim@(Wsc@Wcs) (and sym.)
#define C_SELF 0.34f
#define C_CROSS 0.495f
#define C_DBL  0.165f

typedef float f32x16 __attribute__((ext_vector_type(16)));
typedef float f32x2 __attribute__((ext_vector_type(2)));
typedef short bf16x8 __attribute__((ext_vector_type(8)));

static __device__ __forceinline__ float b2f(unsigned short u) {
  union { unsigned int i; float f; } v; v.i = ((unsigned int)u) << 16; return v.f;
}
static __device__ __forceinline__ unsigned short f2b(float f) {
  union { float f; unsigned int i; } v; v.f = f;
  unsigned int x = v.i;
  return (unsigned short)((x + 0x7fffu + ((x >> 16) & 1u)) >> 16);  // RNE
}
static __device__ __forceinline__ void load4bf(const unsigned short* p, float* d) {
  ushort4 u = *(const ushort4*)p;
  d[0] = b2f(u.x); d[1] = b2f(u.y); d[2] = b2f(u.z); d[3] = b2f(u.w);
}

// ---- DPP cross-lane (VALU pipe, not LDS) ----
template <int CTRL>
static __device__ __forceinline__ float dpp_mov(float x) {
  return __int_as_float(__builtin_amdgcn_update_dpp(
      0, __float_as_int(x), CTRL, 0xF, 0xF, true));
}
// 32-lane sum; valid in lanes 31 (half0) and 63 (half1).
static __device__ __forceinline__ float dpp_sum32_tail(float x) {
  x += dpp_mov<0x111>(x);   // row_shr:1
  x += dpp_mov<0x112>(x);   // row_shr:2
  x += dpp_mov<0x114>(x);   // row_shr:4
  x += dpp_mov<0x118>(x);   // row_shr:8
  x += dpp_mov<0x142>(x);   // row_bcast:15
  return x;
}
// 32-lane all-reduce sum: 4 DPP + 1 swizzle
static __device__ __forceinline__ float allred32_sum(float x) {
  x += dpp_mov<0xB1>(x);
  x += dpp_mov<0x4E>(x);
  x += dpp_mov<0x124>(x);
  x += dpp_mov<0x128>(x);
  x += __int_as_float(__builtin_amdgcn_ds_swizzle(__float_as_int(x), 0x401F));
  return x;
}

// dual-dtype loaders: f32flag=1 -> buffer holds float32, else bf16.
static __device__ __forceinline__ void load4any(const void* base, size_t idx, int f32flag, float* d) {
  if (f32flag) {
    float4 v = *(const float4*)((const float*)base + idx);
    d[0] = v.x; d[1] = v.y; d[2] = v.z; d[3] = v.w;
  } else {
    load4bf((const unsigned short*)base + idx, d);
  }
}
static __device__ __forceinline__ float load1any(const void* base, size_t idx, int f32flag) {
  return f32flag ? ((const float*)base)[idx] : b2f(((const unsigned short*)base)[idx]);
}

// ---- inline flag detection (per wave) ----
static __device__ __forceinline__ int detect_wf(const unsigned short* __restrict__ W) {
  const int l = threadIdx.x & 63;
  int bad = 0;
#pragma unroll
  for (int i = l; i < 128; i += 64) {
    unsigned short u = W[i];
    if (u != 0) {
      int e = (u >> 7) & 0xFF;
      if (e < 90 || e > 128) bad++;
    }
  }
#pragma unroll
  for (int d = 1; d < 64; d <<= 1) bad += __shfl_xor(bad, d);
  return (bad > 8) ? 1 : 0;
}
static __device__ __forceinline__ int detect_x64(const int* __restrict__ x) {
  const int l = threadIdx.x & 63;
  int nz = (l < 16) ? (x[2 * l + 1] != 0 ? 1 : 0) : 0;
#pragma unroll
  for (int d = 1; d < 64; d <<= 1) nz += __shfl_xor(nz, d);
  return (nz == 0) ? 1 : 0;
}

// ---- single fused prep launch ----
// bid<128: WT transposes (2 matrices x 128 cols, 2 cols/block).
// bid 128/129: full matrix chain per block: P = Wo@W1 (PT out, P staged in LDS),
//              M^T = (C_SELF*Wo + C_DBL*(P@W2))^T. B-frags built straight from
//              W1/W2 column loads (identical values to the old WscT/WcsT path).
// bid 130: bias-vector chain (p1/p2 -> bsim/bcor) via LDS.
__global__ __launch_bounds__(256) void prep2(
    const void* __restrict__ Wsim_in, const void* __restrict__ Wcor_in,
    const void* __restrict__ Wos, const void* __restrict__ Woc,
    const void* __restrict__ Wsc, const void* __restrict__ Wcs,
    const void* __restrict__ bs, const void* __restrict__ bc,
    unsigned short* __restrict__ WTsim, unsigned short* __restrict__ WTcor,
    unsigned short* __restrict__ P1T, unsigned short* __restrict__ P2T,
    unsigned short* __restrict__ MssT, unsigned short* __restrict__ MccT,
    float* __restrict__ bsim, float* __restrict__ bcor)
{
  __shared__ unsigned short Pl[128 * 128];   // 32 KB staged P
  __shared__ float l1[256], l2[256], lp1[128], lp2[128];
  const int wf = detect_wf((const unsigned short*)Wsim_in);
  const int bid = blockIdx.x;
  const int t = threadIdx.x;

  if (bid < 128) {
    const int mat = bid >> 6;
    const int n = (bid & 63) * 2 + (t >> 7);
    const int k = t & 127;
    const void* W = mat ? Wcor_in : Wsim_in;
    unsigned short* WT = mat ? WTcor : WTsim;
    WT[n * 128 + k] = f2b(load1any(W, k * 128 + n, wf));
    return;
  }

  if (bid < 130) {
    const int isMcc = bid & 1;
    const void* Wself = isMcc ? Woc : Wos;
    const void* B1 = isMcc ? Wcs : Wsc;
    const void* B2 = isMcc ? Wsc : Wcs;
    unsigned short* PT = isMcc ? P2T : P1T;
    unsigned short* MT = isMcc ? MccT : MssT;

    const int w = t >> 6, l = t & 63, lane = l & 31, half = l >> 5;
    const int n = w * 32 + lane;         // this lane's output column

    // stage-1 B-frags: B[k][n] = W1[k][n], k = s*16 + half*8 + j
    bf16x8 bf[8];
#pragma unroll
    for (int s = 0; s < 8; ++s) {
      union { bf16x8 v; unsigned short u[8]; } cv;
#pragma unroll
      for (int j = 0; j < 8; ++j)
        cv.u[j] = f2b(load1any(B1, (size_t)(s * 16 + half * 8 + j) * 128 + n, wf));
      bf[s] = cv.v;
    }

#pragma unroll
    for (int tr = 0; tr < 4; ++tr) {
      const int ar = tr * 32 + lane;
      bf16x8 af[8];
#pragma unroll
      for (int s = 0; s < 8; ++s) {
        float tmp[8];
        const size_t base = (size_t)ar * 128 + s * 16 + half * 8;
        load4any(Wself, base, wf, tmp);
        load4any(Wself, base + 4, wf, tmp + 4);
        union { bf16x8 v; unsigned short u[8]; } cv;
#pragma unroll
        for (int j = 0; j < 8; ++j) cv.u[j] = f2b(tmp[j]);
        af[s] = cv.v;
      }
      f32x16 acc = {0,0,0,0,0,0,0,0,0,0,0,0,0,0,0,0};
#pragma unroll
      for (int s = 0; s < 8; ++s)
        acc = __builtin_amdgcn_mfma_f32_32x32x16_bf16(af[s], bf[s], acc, 0, 0, 0);
#pragma unroll
      for (int i = 0; i < 16; ++i) {
        const int r = tr * 32 + (i & 3) + 8 * (i >> 2) + 4 * half;
        const unsigned short v = f2b(acc[i]);
        PT[(size_t)n * 128 + r] = v;
        Pl[r * 128 + n] = v;
      }
    }
    __syncthreads();

    // stage-2: M = C_SELF*Wself + C_DBL*(P@W2)
    bf16x8 bf2[8];
#pragma unroll
    for (int s = 0; s < 8; ++s) {
      union { bf16x8 v; unsigned short u[8]; } cv;
#pragma unroll
      for (int j = 0; j < 8; ++j)
        cv.u[j] = f2b(load1any(B2, (size_t)(s * 16 + half * 8 + j) * 128 + n, wf));
      bf2[s] = cv.v;
    }
#pragma unroll
    for (int tr = 0; tr < 4; ++tr) {
      f32x16 acc = {0,0,0,0,0,0,0,0,0,0,0,0,0,0,0,0};
#pragma unroll
      for (int s = 0; s < 8; ++s) {
        bf16x8 af = *(const bf16x8*)(Pl + (tr * 32 + lane) * 128 + s * 16 + half * 8);
        acc = __builtin_amdgcn_mfma_f32_32x32x16_bf16(af, bf2[s], acc, 0, 0, 0);
      }
#pragma unroll
      for (int i = 0; i < 16; ++i) {
        const int r = tr * 32 + (i & 3) + 8 * (i >> 2) + 4 * half;
        MT[(size_t)n * 128 + r] =
            f2b(C_SELF * load1any(Wself, (size_t)r * 128 + n, wf) + C_DBL * acc[i]);
      }
    }
    return;
  }

  // bid == 130: bias vectors
  const int c = t & 127, kg = t >> 7;
  float a1 = 0.f, a2 = 0.f;
  for (int k = kg * 64; k < kg * 64 + 64; ++k) {
    a1 += load1any(bs, k, wf) * load1any(Wsc, k * 128 + c, wf);
    a2 += load1any(bc, k, wf) * load1any(Wcs, k * 128 + c, wf);
  }
  l1[t] = a1; l2[t] = a2;
  __syncthreads();
  if (kg == 0) { lp1[c] = l1[c] + l1[c + 128]; lp2[c] = l2[c] + l2[c + 128]; }
  __syncthreads();
  float a3 = 0.f, a4 = 0.f;
  for (int k = kg * 64; k < kg * 64 + 64; ++k) {
    a3 += lp1[k] * load1any(Wcs, k * 128 + c, wf);
    a4 += lp2[k] * load1any(Wsc, k * 128 + c, wf);
  }
  l1[t] = a3; l2[t] = a4;
  __syncthreads();
  if (kg == 0) {
    bsim[c] = C_SELF * load1any(bs, c, wf) + C_CROSS * lp2[c] + C_DBL * (l1[c] + l1[c + 128]);
    bcor[c] = C_SELF * load1any(bc, c, wf) + C_CROSS * lp1[c] + C_DBL * (l2[c] + l2[c + 128]);
  }
}

// feat = [emb0[x0]|emb1[x1]] @ W + b via bf16 MFMA. Both modes in one launch
// (blockIdx.y selects sim/cor). Block = 4 waves x 32 rows each; each WAVE covers
// all 128 cols in 4 strips, reusing its A fragments (gather+cvt amortized 4x).
// NOTE: do NOT split strips across blocks — emb1 (38 MB) exceeds L2, so re-gather
// misses HBM twice (round-5 regression).
__global__ __launch_bounds__(256) void featgemm_mfma(
    const int* __restrict__ x,
    const void* __restrict__ Wdet,
    const void* __restrict__ emb0s, const void* __restrict__ emb1s,
    const void* __restrict__ emb0c, const void* __restrict__ emb1c,
    const unsigned short* __restrict__ WTs, const unsigned short* __restrict__ WTc,
    const void* __restrict__ bvs, const void* __restrict__ bvc,
    unsigned char* __restrict__ f8s, unsigned short* __restrict__ f16s,
    unsigned char* __restrict__ f8c, unsigned short* __restrict__ f16c)
{
  const int wf  = detect_wf((const unsigned short*)Wdet);
  const int x64 = detect_x64(x);
  const int mode = blockIdx.y;
  const void* emb0 = mode ? emb0c : emb0s;
  const void* emb1 = mode ? emb1c : emb1s;
  const unsigned short* WT = mode ? WTc : WTs;
  const void* bvec = mode ? bvc : bvs;
  unsigned char*  feat8  = mode ? f8c  : f8s;
  unsigned short* feat16 = mode ? f16c : f16s;

  const int t = threadIdx.x;
  const int w = t >> 6, l = t & 63, lane = l & 31, half = l >> 5;
  const int rbase = blockIdx.x * 128 + w * 32;
  const int r = rbase + lane;            // A row this lane gathers

  int x0, x1;
  if (x64) { x0 = x[r * 4]; x1 = x[r * 4 + 2]; }
  else     { x0 = x[r * 2]; x1 = x[r * 2 + 1]; }

  bf16x8 afrag[8];
#pragma unroll
  for (int s = 0; s < 8; ++s) {
    float tmp[8];
    if (s < 2) {
      const size_t base = (size_t)x0 * 32 + s * 16 + half * 8;
      load4any(emb0, base, wf, tmp);
      load4any(emb0, base + 4, wf, tmp + 4);
    } else {
      const size_t base = (size_t)x1 * 96 + (s * 16 - 32) + half * 8;
      load4any(emb1, base, wf, tmp);
      load4any(emb1, base + 4, wf, tmp + 4);
    }
    union { bf16x8 v; unsigned short u[8]; } cv;
#pragma unroll
    for (int j = 0; j < 8; ++j) cv.u[j] = f2b(tmp[j]);
    afrag[s] = cv.v;
  }

  const bool do16 = (rbase < NDST);
#pragma unroll
  for (int strip = 0; strip < 4; ++strip) {
    const int n = strip * 32 + lane;
    const unsigned short* wtrow = WT + (size_t)n * 128 + half * 8;
    f32x16 acc = {0,0,0,0,0,0,0,0,0,0,0,0,0,0,0,0};
#pragma unroll
    for (int s = 0; s < 8; ++s) {
      bf16x8 bfrag = *(const bf16x8*)(wtrow + s * 16);
      acc = __builtin_amdgcn_mfma_f32_32x32x16_bf16(afrag[s], bfrag, acc, 0, 0, 0);
    }
    const float bias_n = load1any(bvec, n, wf);
#pragma unroll
    for (int i = 0; i < 16; ++i) {
      const int m = (i & 3) + 8 * (i >> 2) + 4 * half;
      const int row = rbase + m;
      const float val = acc[i] + bias_n;
      const int p8 = __builtin_amdgcn_cvt_pk_fp8_f32(val, val, 0, false);
      feat8[(size_t)row * H + n] = (unsigned char)(p8 & 0xFF);
      if (do16) feat16[(size_t)row * H + n] = f2b(val);
    }
  }
}

// Collapsed co-attention pool, one WAVE per node; both modes in one launch.
// fp8 gather + fp8 MFMA + DPP reductions; pooled sums via identity-B transpose-MFMA.
// __launch_bounds__(256,8): cap VGPR at 64 (was 68) -> 8 waves/SIMD residency for
// gather-latency hiding.
__global__ __launch_bounds__(256, 8) void coatt_mfma(
    const unsigned char* __restrict__ f8s, const unsigned short* __restrict__ f16s,
    const unsigned char* __restrict__ f8c, const unsigned short* __restrict__ f16c,
    const int* __restrict__ nsim, const int* __restrict__ ncor,
    unsigned short* __restrict__ rsts, unsigned short* __restrict__ rstc)
{
  const int mode = blockIdx.y;
  const unsigned char*  feat8  = mode ? f8c  : f8s;
  const unsigned short* feat16 = mode ? f16c : f16s;
  const int* idxD = mode ? nsim : ncor;   // 'sim': D=neigh_cor; 'cor': D=neigh_sim
  const int* idxQ = mode ? ncor : nsim;
  unsigned short* rst = mode ? rstc : rsts;

  __shared__ float gbuf[4][448];   // per wave: g[384] | sv[32] | tv[32]
  const int t = threadIdx.x;
  const int w = t >> 6;            // wave in block
  const int l = t & 63;            // lane
  const int r = l & 31;            // row index within D/Q tiles
  const int half = l >> 5;
  const int n = blockIdx.x * 4 + w;

  float* g   = gbuf[w];
  float* svb = gbuf[w] + 384;
  float* tvb = gbuf[w] + 416;

  const int gD = idxD[n * 32 + r];
  const int gQ = idxQ[n * 32 + r];
  const unsigned char* drow = feat8 + (size_t)gD * H + half * 8;
  const unsigned char* qrow = feat8 + (size_t)gQ * H + half * 8;

  long dfrag[8], qfrag[8];
#pragma unroll
  for (int s = 0; s < 8; ++s) {
    dfrag[s] = *(const long*)(drow + s * 16);
    qfrag[s] = *(const long*)(qrow + s * 16);
  }

  f32x16 acc = {0,0,0,0,0,0,0,0,0,0,0,0,0,0,0,0};
#pragma unroll
  for (int s = 0; s < 8; ++s)
    acc = __builtin_amdgcn_mfma_f32_32x32x16_fp8_fp8(dfrag[s], qfrag[s], acc, 0, 0, 0);
  // L[m][k]: col k = l&31, row m = (reg&3) + 8*(reg>>2) + 4*half

  float ex[16], rrcp[16];
#pragma unroll
  for (int i = 0; i < 16; ++i) ex[i] = __expf(acc[i]);
#pragma unroll
  for (int i = 0; i < 16; ++i) rrcp[i] = 1.0f / allred32_sum(ex[i]);
  float csum = 0.f;
#pragma unroll
  for (int i = 0; i < 16; ++i) csum += ex[i];
  csum += __shfl_xor(csum, 32);
  const float crcp = 1.0f / csum;

  float svt[16];
#pragma unroll
  for (int i = 0; i < 16; ++i) svt[i] = dpp_sum32_tail(ex[i] * crcp);
  if (r == 31) {
    *(float4*)(svb + 4 * half)      = make_float4(svt[0],  svt[1],  svt[2],  svt[3]);
    *(float4*)(svb + 8 + 4 * half)  = make_float4(svt[4],  svt[5],  svt[6],  svt[7]);
    *(float4*)(svb + 16 + 4 * half) = make_float4(svt[8],  svt[9],  svt[10], svt[11]);
    *(float4*)(svb + 24 + 4 * half) = make_float4(svt[12], svt[13], svt[14], svt[15]);
  }
  float sv16[16];
#pragma unroll
  for (int q = 0; q < 4; ++q) {
    float4 v = *(const float4*)(svb + q * 8 + 4 * half);
    sv16[q * 4] = v.x; sv16[q * 4 + 1] = v.y; sv16[q * 4 + 2] = v.z; sv16[q * 4 + 3] = v.w;
  }
  float tvp = 0.f;
#pragma unroll
  for (int i = 0; i < 16; ++i) tvp += sv16[i] * ex[i] * rrcp[i];
  const float tv = tvp + __shfl_xor(tvp, 32);

  if (l < 32) tvb[l] = tv;
  float tv16[16];
#pragma unroll
  for (int q = 0; q < 4; ++q) {
    float4 vv = *(const float4*)(tvb + q * 8 + 4 * half);
    tv16[q * 4] = vv.x; tv16[q * 4 + 1] = vv.y; tv16[q * 4 + 2] = vv.z; tv16[q * 4 + 3] = vv.w;
  }

  // ---- pooled: g = [u | v | w] via transpose-MFMA; float2 accumulation ----
  const int bpos = (l & 15) - half * 8;
  const long b_ident = (bpos >= 0 && bpos < 8) ? (0x38L << (8 * bpos)) : 0L;
  const f32x16 zf = {0,0,0,0,0,0,0,0,0,0,0,0,0,0,0,0};

#pragma unroll
  for (int s = 0; s < 8; ++s) {
    f32x16 td = __builtin_amdgcn_mfma_f32_32x32x16_fp8_fp8(dfrag[s], b_ident, zf, 0, 0, 0);
    f32x16 tq = __builtin_amdgcn_mfma_f32_32x32x16_fp8_fp8(qfrag[s], b_ident, zf, 0, 0, 0);
    f32x2 su2 = {0.f, 0.f}, sw2 = {0.f, 0.f}, sv2 = {0.f, 0.f};
#pragma unroll
    for (int i = 0; i < 8; ++i) {
      f32x2 tq2 = { tq[2 * i], tq[2 * i + 1] };
      f32x2 td2 = { td[2 * i], td[2 * i + 1] };
      f32x2 tvv = { tv16[2 * i], tv16[2 * i + 1] };
      f32x2 svv = { sv16[2 * i], sv16[2 * i + 1] };
      su2 += tq2;
      sw2 += tvv * tq2;
      sv2 += svv * td2;
    }
    float su = su2.x + su2.y, sw = sw2.x + sw2.y, sv_ = sv2.x + sv2.y;
    su  += __shfl_xor(su, 32);
    sw  += __shfl_xor(sw, 32);
    sv_ += __shfl_xor(sv_, 32);
    if (l < 16) {
      const int c = s * 16 + l;
      g[c]       = su;
      g[128 + c] = sv_;
      g[256 + c] = sw;
    }
  }

#pragma unroll
  for (int rep = 0; rep < 2; ++rep) {
    const int hp = l + rep * 64;
    const float p = (g[3 * hp] + g[3 * hp + 1] + g[3 * hp + 2]) * (1.0f / 96.0f);
    const float hs = b2f(feat16[(size_t)n * H + hp]);
    rst[(size_t)n * H + hp] = f2b(hs + p);
  }
}

// z2sim = Rs@Mss + C_CROSS*(Rc@P2) + bsim ; z2cor = Rc@Mcc + C_CROSS*(Rs@P1) + bcor.
// Transposed orientation: A = MssT/P1T rows (n in reg dim), B = Rs/Rc rows (row in
// lane dim) -> C[i][lane] has consecutive n per reg group => packed float4 stores.
__global__ __launch_bounds__(256) void finalmm_mfma(
    const unsigned short* __restrict__ Rs, const unsigned short* __restrict__ Rc,
    const unsigned short* __restrict__ MssT, const unsigned short* __restrict__ MccT,
    const unsigned short* __restrict__ P1T, const unsigned short* __restrict__ P2T,
    const float* __restrict__ bsim, const float* __restrict__ bcor,
    float* __restrict__ outp)
{
  const int t = threadIdx.x;
  const int w = t >> 6, l = t & 63, lane = l & 31, half = l >> 5;
  const int rbase = blockIdx.x * 32;
  const int orow = rbase + lane;   // output row this lane owns (B gather row)
  const int nb = w * 32;           // this wave's n-strip

  const unsigned short* rsrow = Rs + (size_t)orow * H + half * 8;
  const unsigned short* rcrow = Rc + (size_t)orow * H + half * 8;
  bf16x8 bS[8], bC[8];
#pragma unroll
  for (int s = 0; s < 8; ++s) {
    bS[s] = *(const bf16x8*)(rsrow + s * 16);
    bC[s] = *(const bf16x8*)(rcrow + s * 16);
  }

  const unsigned short* aMss = MssT + (size_t)(nb + lane) * 128 + half * 8;
  const unsigned short* aMcc = MccT + (size_t)(nb + lane) * 128 + half * 8;
  const unsigned short* aP1  = P1T  + (size_t)(nb + lane) * 128 + half * 8;
  const unsigned short* aP2  = P2T  + (size_t)(nb + lane) * 128 + half * 8;

  f32x16 a1 = {0,0,0,0,0,0,0,0,0,0,0,0,0,0,0,0};   // (Rs@Mss)^T
  f32x16 a2 = a1, a3 = a1, a4 = a1;                 // (Rc@P2)^T, (Rc@Mcc)^T, (Rs@P1)^T
#pragma unroll
  for (int s = 0; s < 8; ++s) {
    bf16x8 m1 = *(const bf16x8*)(aMss + s * 16);
    bf16x8 m2 = *(const bf16x8*)(aP2  + s * 16);
    bf16x8 m3 = *(const bf16x8*)(aMcc + s * 16);
    bf16x8 m4 = *(const bf16x8*)(aP1  + s * 16);
    a1 = __builtin_amdgcn_mfma_f32_32x32x16_bf16(m1, bS[s], a1, 0, 0, 0);
    a2 = __builtin_amdgcn_mfma_f32_32x32x16_bf16(m2, bC[s], a2, 0, 0, 0);
    a3 = __builtin_amdgcn_mfma_f32_32x32x16_bf16(m3, bC[s], a3, 0, 0, 0);
    a4 = __builtin_amdgcn_mfma_f32_32x32x16_bf16(m4, bS[s], a4, 0, 0, 0);
  }

  // C[i][lane]: n = nb + (i&3) + 8*(i>>2) + 4*half -> consecutive per 4-reg group
#pragma unroll
  for (int q = 0; q < 4; ++q) {
    const int n0 = nb + 8 * q + 4 * half;
    const float4 bsv = *(const float4*)(bsim + n0);
    const float4 bcv = *(const float4*)(bcor + n0);
    float4 v1, v2;
    v1.x = a1[4*q+0] + C_CROSS * a2[4*q+0] + bsv.x;
    v1.y = a1[4*q+1] + C_CROSS * a2[4*q+1] + bsv.y;
    v1.z = a1[4*q+2] + C_CROSS * a2[4*q+2] + bsv.z;
    v1.w = a1[4*q+3] + C_CROSS * a2[4*q+3] + bsv.w;
    v2.x = a3[4*q+0] + C_CROSS * a4[4*q+0] + bcv.x;
    v2.y = a3[4*q+1] + C_CROSS * a4[4*q+1] + bcv.y;
    v2.z = a3[4*q+2] + C_CROSS * a4[4*q+2] + bcv.z;
    v2.w = a3[4*q+3] + C_CROSS * a4[4*q+3] + bcv.w;
    *(float4*)(outp + (size_t)orow * H + n0) = v1;
    *(float4*)(outp + (size_t)NDST * H + (size_t)orow * H + n0) = v2;
  }
}

extern "C" void kernel_launch(void* const* d_in, const int* in_sizes, int n_in,
                              void* d_out, int out_size, void* d_ws, size_t ws_size,
                              hipStream_t stream) {
  const int* x    = (const int*)d_in[0];
  const int* nsim = (const int*)d_in[1];
  const int* ncor = (const int*)d_in[2];
  const void* emb0_sim = d_in[3];
  const void* emb1_sim = d_in[4];
  const void* emb0_cor = d_in[5];
  const void* emb1_cor = d_in[6];
  const void* W_in_sim  = d_in[7];
  const void* b_in_sim  = d_in[8];
  const void* W_in_cor  = d_in[9];
  const void* b_in_cor  = d_in[10];
  const void* W_out_sim = d_in[11];
  const void* b_out_sim = d_in[12];
  const void* W_out_cor = d_in[13];
  const void* b_out_cor = d_in[14];
  const void* W_sim2cor = d_in[15];
  const void* W_cor2sim = d_in[16];

  float* fbase = (float*)d_ws;
  float* P1slot = fbase;                // unused scratch slots (layout kept stable)
  float* P2slot = P1slot + H * H;
  float* p1v = P2slot + H * H;
  float* p2v = p1v + H;
  float* bsimv = p2v + H;
  float* bcorv = bsimv + H;
  int* flags = (int*)(bcorv + H);
  unsigned short* feat16_sim = (unsigned short*)(flags + 4);     // NDST*H
  unsigned short* feat16_cor = feat16_sim + (size_t)NDST * H;
  unsigned short* rst_sim    = feat16_cor + (size_t)NDST * H;
  unsigned short* rst_cor    = rst_sim + (size_t)NDST * H;
  unsigned char* feat8_sim = (unsigned char*)(rst_cor + (size_t)NDST * H);  // NSRC*H
  unsigned char* feat8_cor = feat8_sim + (size_t)NSRC * H;
  unsigned short* WT_sim = (unsigned short*)(feat8_cor + (size_t)NSRC * H);
  unsigned short* WT_cor = WT_sim + H * H;
  unsigned short* P1T  = WT_cor + H * H;
  unsigned short* P2T  = P1T + H * H;
  unsigned short* MssT = P2T + H * H;
  unsigned short* MccT = MssT + H * H;

  prep2<<<131, 256, 0, stream>>>(W_in_sim, W_in_cor, W_out_sim, W_out_cor,
                                 W_sim2cor, W_cor2sim, b_out_sim, b_out_cor,
                                 WT_sim, WT_cor, P1T, P2T, MssT, MccT, bsimv, bcorv);
  featgemm_mfma<<<dim3(NSRC / 128, 2), 256, 0, stream>>>(
      x, W_in_sim, emb0_sim, emb1_sim, emb0_cor, emb1_cor,
      WT_sim, WT_cor, b_in_sim, b_in_cor,
      feat8_sim, feat16_sim, feat8_cor, feat16_cor);
  coatt_mfma<<<dim3(NDST / 4, 2), 256, 0, stream>>>(
      feat8_sim, feat16_sim, feat8_cor, feat16_cor,
      nsim, ncor, rst_sim, rst_cor);
  finalmm_mfma<<<NDST / 32, 256, 0, stream>>>(rst_sim, rst_cor, MssT, MccT, P1T, P2T,
                                              bsimv, bcorv, (float*)d_out);
}

// Round 8
// 245.394 us; speedup vs baseline: 1.3272x; 1.3272x over previous
//
#include <hip/hip_runtime.h>
#include <hip/hip_bf16.h>

#define NSRC 65536
#define NDST 8192
#define H 128

// mixing constants: z2sim = 0.34*sim + 0.495*cor@Wcs + 0.165*sim@(Wsc@Wcs) (and sym.)
#define C_SELF 0.34f
#define C_CROSS 0.495f
#define C_DBL  0.165f

typedef float f32x16 __attribute__((ext_vector_type(16)));
typedef float f32x2 __attribute__((ext_vector_type(2)));
typedef short bf16x8 __attribute__((ext_vector_type(8)));

static __device__ __forceinline__ float b2f(unsigned short u) {
  union { unsigned int i; float f; } v; v.i = ((unsigned int)u) << 16; return v.f;
}
static __device__ __forceinline__ unsigned short f2b(float f) {
  union { float f; unsigned int i; } v; v.f = f;
  unsigned int x = v.i;
  return (unsigned short)((x + 0x7fffu + ((x >> 16) & 1u)) >> 16);  // RNE
}
static __device__ __forceinline__ void load4bf(const unsigned short* p, float* d) {
  ushort4 u = *(const ushort4*)p;
  d[0] = b2f(u.x); d[1] = b2f(u.y); d[2] = b2f(u.z); d[3] = b2f(u.w);
}

// ---- DPP cross-lane (VALU pipe, not LDS) ----
template <int CTRL>
static __device__ __forceinline__ float dpp_mov(float x) {
  return __int_as_float(__builtin_amdgcn_update_dpp(
      0, __float_as_int(x), CTRL, 0xF, 0xF, true));
}
// 32-lane sum; valid in lanes 31 (half0) and 63 (half1).
static __device__ __forceinline__ float dpp_sum32_tail(float x) {
  x += dpp_mov<0x111>(x);   // row_shr:1
  x += dpp_mov<0x112>(x);   // row_shr:2
  x += dpp_mov<0x114>(x);   // row_shr:4
  x += dpp_mov<0x118>(x);   // row_shr:8
  x += dpp_mov<0x142>(x);   // row_bcast:15
  return x;
}
// 32-lane all-reduce sum: 4 DPP + 1 swizzle
static __device__ __forceinline__ float allred32_sum(float x) {
  x += dpp_mov<0xB1>(x);
  x += dpp_mov<0x4E>(x);
  x += dpp_mov<0x124>(x);
  x += dpp_mov<0x128>(x);
  x += __int_as_float(__builtin_amdgcn_ds_swizzle(__float_as_int(x), 0x401F));
  return x;
}

// dual-dtype loaders: f32flag=1 -> buffer holds float32, else bf16.
static __device__ __forceinline__ void load4any(const void* base, size_t idx, int f32flag, float* d) {
  if (f32flag) {
    float4 v = *(const float4*)((const float*)base + idx);
    d[0] = v.x; d[1] = v.y; d[2] = v.z; d[3] = v.w;
  } else {
    load4bf((const unsigned short*)base + idx, d);
  }
}
static __device__ __forceinline__ float load1any(const void* base, size_t idx, int f32flag) {
  return f32flag ? ((const float*)base)[idx] : b2f(((const unsigned short*)base)[idx]);
}

// ---- inline flag detection (per wave) ----
static __device__ __forceinline__ int detect_wf(const unsigned short* __restrict__ W) {
  const int l = threadIdx.x & 63;
  int bad = 0;
#pragma unroll
  for (int i = l; i < 128; i += 64) {
    unsigned short u = W[i];
    if (u != 0) {
      int e = (u >> 7) & 0xFF;
      if (e < 90 || e > 128) bad++;
    }
  }
#pragma unroll
  for (int d = 1; d < 64; d <<= 1) bad += __shfl_xor(bad, d);
  return (bad > 8) ? 1 : 0;
}
static __device__ __forceinline__ int detect_x64(const int* __restrict__ x) {
  const int l = threadIdx.x & 63;
  int nz = (l < 16) ? (x[2 * l + 1] != 0 ? 1 : 0) : 0;
#pragma unroll
  for (int d = 1; d < 64; d <<= 1) nz += __shfl_xor(nz, d);
  return (nz == 0) ? 1 : 0;
}

// ---- single fused prep launch ----
// bid<128: WT transposes (2 matrices x 128 cols, 2 cols/block).
// bid 128/129: full matrix chain per block: P = Wo@W1 (PT out, P staged in LDS),
//              M^T = (C_SELF*Wo + C_DBL*(P@W2))^T. B-frags built straight from
//              W1/W2 column loads (identical values to the old WscT/WcsT path).
// bid 130: bias-vector chain (p1/p2 -> bsim/bcor) via LDS.
__global__ __launch_bounds__(256) void prep2(
    const void* __restrict__ Wsim_in, const void* __restrict__ Wcor_in,
    const void* __restrict__ Wos, const void* __restrict__ Woc,
    const void* __restrict__ Wsc, const void* __restrict__ Wcs,
    const void* __restrict__ bs, const void* __restrict__ bc,
    unsigned short* __restrict__ WTsim, unsigned short* __restrict__ WTcor,
    unsigned short* __restrict__ P1T, unsigned short* __restrict__ P2T,
    unsigned short* __restrict__ MssT, unsigned short* __restrict__ MccT,
    float* __restrict__ bsim, float* __restrict__ bcor)
{
  __shared__ unsigned short Pl[128 * 128];   // 32 KB staged P
  __shared__ float l1[256], l2[256], lp1[128], lp2[128];
  const int wf = detect_wf((const unsigned short*)Wsim_in);
  const int bid = blockIdx.x;
  const int t = threadIdx.x;

  if (bid < 128) {
    const int mat = bid >> 6;
    const int n = (bid & 63) * 2 + (t >> 7);
    const int k = t & 127;
    const void* W = mat ? Wcor_in : Wsim_in;
    unsigned short* WT = mat ? WTcor : WTsim;
    WT[n * 128 + k] = f2b(load1any(W, k * 128 + n, wf));
    return;
  }

  if (bid < 130) {
    const int isMcc = bid & 1;
    const void* Wself = isMcc ? Woc : Wos;
    const void* B1 = isMcc ? Wcs : Wsc;
    const void* B2 = isMcc ? Wsc : Wcs;
    unsigned short* PT = isMcc ? P2T : P1T;
    unsigned short* MT = isMcc ? MccT : MssT;

    const int w = t >> 6, l = t & 63, lane = l & 31, half = l >> 5;
    const int n = w * 32 + lane;         // this lane's output column

    // stage-1 B-frags: B[k][n] = W1[k][n], k = s*16 + half*8 + j
    bf16x8 bf[8];
#pragma unroll
    for (int s = 0; s < 8; ++s) {
      union { bf16x8 v; unsigned short u[8]; } cv;
#pragma unroll
      for (int j = 0; j < 8; ++j)
        cv.u[j] = f2b(load1any(B1, (size_t)(s * 16 + half * 8 + j) * 128 + n, wf));
      bf[s] = cv.v;
    }

#pragma unroll
    for (int tr = 0; tr < 4; ++tr) {
      const int ar = tr * 32 + lane;
      bf16x8 af[8];
#pragma unroll
      for (int s = 0; s < 8; ++s) {
        float tmp[8];
        const size_t base = (size_t)ar * 128 + s * 16 + half * 8;
        load4any(Wself, base, wf, tmp);
        load4any(Wself, base + 4, wf, tmp + 4);
        union { bf16x8 v; unsigned short u[8]; } cv;
#pragma unroll
        for (int j = 0; j < 8; ++j) cv.u[j] = f2b(tmp[j]);
        af[s] = cv.v;
      }
      f32x16 acc = {0,0,0,0,0,0,0,0,0,0,0,0,0,0,0,0};
#pragma unroll
      for (int s = 0; s < 8; ++s)
        acc = __builtin_amdgcn_mfma_f32_32x32x16_bf16(af[s], bf[s], acc, 0, 0, 0);
#pragma unroll
      for (int i = 0; i < 16; ++i) {
        const int r = tr * 32 + (i & 3) + 8 * (i >> 2) + 4 * half;
        const unsigned short v = f2b(acc[i]);
        PT[(size_t)n * 128 + r] = v;
        Pl[r * 128 + n] = v;
      }
    }
    __syncthreads();

    // stage-2: M = C_SELF*Wself + C_DBL*(P@W2)
    bf16x8 bf2[8];
#pragma unroll
    for (int s = 0; s < 8; ++s) {
      union { bf16x8 v; unsigned short u[8]; } cv;
#pragma unroll
      for (int j = 0; j < 8; ++j)
        cv.u[j] = f2b(load1any(B2, (size_t)(s * 16 + half * 8 + j) * 128 + n, wf));
      bf2[s] = cv.v;
    }
#pragma unroll
    for (int tr = 0; tr < 4; ++tr) {
      f32x16 acc = {0,0,0,0,0,0,0,0,0,0,0,0,0,0,0,0};
#pragma unroll
      for (int s = 0; s < 8; ++s) {
        bf16x8 af = *(const bf16x8*)(Pl + (tr * 32 + lane) * 128 + s * 16 + half * 8);
        acc = __builtin_amdgcn_mfma_f32_32x32x16_bf16(af, bf2[s], acc, 0, 0, 0);
      }
#pragma unroll
      for (int i = 0; i < 16; ++i) {
        const int r = tr * 32 + (i & 3) + 8 * (i >> 2) + 4 * half;
        MT[(size_t)n * 128 + r] =
            f2b(C_SELF * load1any(Wself, (size_t)r * 128 + n, wf) + C_DBL * acc[i]);
      }
    }
    return;
  }

  // bid == 130: bias vectors
  const int c = t & 127, kg = t >> 7;
  float a1 = 0.f, a2 = 0.f;
  for (int k = kg * 64; k < kg * 64 + 64; ++k) {
    a1 += load1any(bs, k, wf) * load1any(Wsc, k * 128 + c, wf);
    a2 += load1any(bc, k, wf) * load1any(Wcs, k * 128 + c, wf);
  }
  l1[t] = a1; l2[t] = a2;
  __syncthreads();
  if (kg == 0) { lp1[c] = l1[c] + l1[c + 128]; lp2[c] = l2[c] + l2[c + 128]; }
  __syncthreads();
  float a3 = 0.f, a4 = 0.f;
  for (int k = kg * 64; k < kg * 64 + 64; ++k) {
    a3 += lp1[k] * load1any(Wcs, k * 128 + c, wf);
    a4 += lp2[k] * load1any(Wsc, k * 128 + c, wf);
  }
  l1[t] = a3; l2[t] = a4;
  __syncthreads();
  if (kg == 0) {
    bsim[c] = C_SELF * load1any(bs, c, wf) + C_CROSS * lp2[c] + C_DBL * (l1[c] + l1[c + 128]);
    bcor[c] = C_SELF * load1any(bc, c, wf) + C_CROSS * lp1[c] + C_DBL * (l2[c] + l2[c + 128]);
  }
}

// feat = [emb0[x0]|emb1[x1]] @ W + b via bf16 MFMA. Both modes in one launch
// (blockIdx.y selects sim/cor). Block = 4 waves x 32 rows each; each WAVE covers
// all 128 cols in 4 strips, reusing its A fragments (gather+cvt amortized 4x).
// NOTE: do NOT split strips across blocks — emb1 (38 MB) exceeds L2, so re-gather
// misses HBM twice (round-5 regression).
__global__ __launch_bounds__(256) void featgemm_mfma(
    const int* __restrict__ x,
    const void* __restrict__ Wdet,
    const void* __restrict__ emb0s, const void* __restrict__ emb1s,
    const void* __restrict__ emb0c, const void* __restrict__ emb1c,
    const unsigned short* __restrict__ WTs, const unsigned short* __restrict__ WTc,
    const void* __restrict__ bvs, const void* __restrict__ bvc,
    unsigned char* __restrict__ f8s, unsigned short* __restrict__ f16s,
    unsigned char* __restrict__ f8c, unsigned short* __restrict__ f16c)
{
  const int wf  = detect_wf((const unsigned short*)Wdet);
  const int x64 = detect_x64(x);
  const int mode = blockIdx.y;
  const void* emb0 = mode ? emb0c : emb0s;
  const void* emb1 = mode ? emb1c : emb1s;
  const unsigned short* WT = mode ? WTc : WTs;
  const void* bvec = mode ? bvc : bvs;
  unsigned char*  feat8  = mode ? f8c  : f8s;
  unsigned short* feat16 = mode ? f16c : f16s;

  const int t = threadIdx.x;
  const int w = t >> 6, l = t & 63, lane = l & 31, half = l >> 5;
  const int rbase = blockIdx.x * 128 + w * 32;
  const int r = rbase + lane;            // A row this lane gathers

  int x0, x1;
  if (x64) { x0 = x[r * 4]; x1 = x[r * 4 + 2]; }
  else     { x0 = x[r * 2]; x1 = x[r * 2 + 1]; }

  bf16x8 afrag[8];
#pragma unroll
  for (int s = 0; s < 8; ++s) {
    float tmp[8];
    if (s < 2) {
      const size_t base = (size_t)x0 * 32 + s * 16 + half * 8;
      load4any(emb0, base, wf, tmp);
      load4any(emb0, base + 4, wf, tmp + 4);
    } else {
      const size_t base = (size_t)x1 * 96 + (s * 16 - 32) + half * 8;
      load4any(emb1, base, wf, tmp);
      load4any(emb1, base + 4, wf, tmp + 4);
    }
    union { bf16x8 v; unsigned short u[8]; } cv;
#pragma unroll
    for (int j = 0; j < 8; ++j) cv.u[j] = f2b(tmp[j]);
    afrag[s] = cv.v;
  }

  const bool do16 = (rbase < NDST);
#pragma unroll
  for (int strip = 0; strip < 4; ++strip) {
    const int n = strip * 32 + lane;
    const unsigned short* wtrow = WT + (size_t)n * 128 + half * 8;
    f32x16 acc = {0,0,0,0,0,0,0,0,0,0,0,0,0,0,0,0};
#pragma unroll
    for (int s = 0; s < 8; ++s) {
      bf16x8 bfrag = *(const bf16x8*)(wtrow + s * 16);
      acc = __builtin_amdgcn_mfma_f32_32x32x16_bf16(afrag[s], bfrag, acc, 0, 0, 0);
    }
    const float bias_n = load1any(bvec, n, wf);
#pragma unroll
    for (int i = 0; i < 16; ++i) {
      const int m = (i & 3) + 8 * (i >> 2) + 4 * half;
      const int row = rbase + m;
      const float val = acc[i] + bias_n;
      const int p8 = __builtin_amdgcn_cvt_pk_fp8_f32(val, val, 0, false);
      feat8[(size_t)row * H + n] = (unsigned char)(p8 & 0xFF);
      if (do16) feat16[(size_t)row * H + n] = f2b(val);
    }
  }
}

// Collapsed co-attention pool, one WAVE per node; both modes in one launch.
// fp8 gather + fp8 MFMA + DPP reductions; pooled sums via identity-B transpose-MFMA.
// Plain __launch_bounds__(256): round-7 showed (256,8) caps VGPR at 32 -> massive
// scratch spill (WRITE_SIZE 4MB->254MB, 51.6->136.8us). Never starve this kernel.
__global__ __launch_bounds__(256) void coatt_mfma(
    const unsigned char* __restrict__ f8s, const unsigned short* __restrict__ f16s,
    const unsigned char* __restrict__ f8c, const unsigned short* __restrict__ f16c,
    const int* __restrict__ nsim, const int* __restrict__ ncor,
    unsigned short* __restrict__ rsts, unsigned short* __restrict__ rstc)
{
  const int mode = blockIdx.y;
  const unsigned char*  feat8  = mode ? f8c  : f8s;
  const unsigned short* feat16 = mode ? f16c : f16s;
  const int* idxD = mode ? nsim : ncor;   // 'sim': D=neigh_cor; 'cor': D=neigh_sim
  const int* idxQ = mode ? ncor : nsim;
  unsigned short* rst = mode ? rstc : rsts;

  __shared__ float gbuf[4][448];   // per wave: g[384] | sv[32] | tv[32]
  const int t = threadIdx.x;
  const int w = t >> 6;            // wave in block
  const int l = t & 63;            // lane
  const int r = l & 31;            // row index within D/Q tiles
  const int half = l >> 5;
  const int n = blockIdx.x * 4 + w;

  float* g   = gbuf[w];
  float* svb = gbuf[w] + 384;
  float* tvb = gbuf[w] + 416;

  const int gD = idxD[n * 32 + r];
  const int gQ = idxQ[n * 32 + r];
  const unsigned char* drow = feat8 + (size_t)gD * H + half * 8;
  const unsigned char* qrow = feat8 + (size_t)gQ * H + half * 8;

  long dfrag[8], qfrag[8];
#pragma unroll
  for (int s = 0; s < 8; ++s) {
    dfrag[s] = *(const long*)(drow + s * 16);
    qfrag[s] = *(const long*)(qrow + s * 16);
  }

  f32x16 acc = {0,0,0,0,0,0,0,0,0,0,0,0,0,0,0,0};
#pragma unroll
  for (int s = 0; s < 8; ++s)
    acc = __builtin_amdgcn_mfma_f32_32x32x16_fp8_fp8(dfrag[s], qfrag[s], acc, 0, 0, 0);
  // L[m][k]: col k = l&31, row m = (reg&3) + 8*(reg>>2) + 4*half

  float ex[16], rrcp[16];
#pragma unroll
  for (int i = 0; i < 16; ++i) ex[i] = __expf(acc[i]);
#pragma unroll
  for (int i = 0; i < 16; ++i) rrcp[i] = 1.0f / allred32_sum(ex[i]);
  float csum = 0.f;
#pragma unroll
  for (int i = 0; i < 16; ++i) csum += ex[i];
  csum += __shfl_xor(csum, 32);
  const float crcp = 1.0f / csum;

  float svt[16];
#pragma unroll
  for (int i = 0; i < 16; ++i) svt[i] = dpp_sum32_tail(ex[i] * crcp);
  if (r == 31) {
    *(float4*)(svb + 4 * half)      = make_float4(svt[0],  svt[1],  svt[2],  svt[3]);
    *(float4*)(svb + 8 + 4 * half)  = make_float4(svt[4],  svt[5],  svt[6],  svt[7]);
    *(float4*)(svb + 16 + 4 * half) = make_float4(svt[8],  svt[9],  svt[10], svt[11]);
    *(float4*)(svb + 24 + 4 * half) = make_float4(svt[12], svt[13], svt[14], svt[15]);
  }
  float sv16[16];
#pragma unroll
  for (int q = 0; q < 4; ++q) {
    float4 v = *(const float4*)(svb + q * 8 + 4 * half);
    sv16[q * 4] = v.x; sv16[q * 4 + 1] = v.y; sv16[q * 4 + 2] = v.z; sv16[q * 4 + 3] = v.w;
  }
  float tvp = 0.f;
#pragma unroll
  for (int i = 0; i < 16; ++i) tvp += sv16[i] * ex[i] * rrcp[i];
  const float tv = tvp + __shfl_xor(tvp, 32);

  if (l < 32) tvb[l] = tv;
  float tv16[16];
#pragma unroll
  for (int q = 0; q < 4; ++q) {
    float4 vv = *(const float4*)(tvb + q * 8 + 4 * half);
    tv16[q * 4] = vv.x; tv16[q * 4 + 1] = vv.y; tv16[q * 4 + 2] = vv.z; tv16[q * 4 + 3] = vv.w;
  }

  // ---- pooled: g = [u | v | w] via transpose-MFMA; float2 accumulation ----
  const int bpos = (l & 15) - half * 8;
  const long b_ident = (bpos >= 0 && bpos < 8) ? (0x38L << (8 * bpos)) : 0L;
  const f32x16 zf = {0,0,0,0,0,0,0,0,0,0,0,0,0,0,0,0};

#pragma unroll
  for (int s = 0; s < 8; ++s) {
    f32x16 td = __builtin_amdgcn_mfma_f32_32x32x16_fp8_fp8(dfrag[s], b_ident, zf, 0, 0, 0);
    f32x16 tq = __builtin_amdgcn_mfma_f32_32x32x16_fp8_fp8(qfrag[s], b_ident, zf, 0, 0, 0);
    f32x2 su2 = {0.f, 0.f}, sw2 = {0.f, 0.f}, sv2 = {0.f, 0.f};
#pragma unroll
    for (int i = 0; i < 8; ++i) {
      f32x2 tq2 = { tq[2 * i], tq[2 * i + 1] };
      f32x2 td2 = { td[2 * i], td[2 * i + 1] };
      f32x2 tvv = { tv16[2 * i], tv16[2 * i + 1] };
      f32x2 svv = { sv16[2 * i], sv16[2 * i + 1] };
      su2 += tq2;
      sw2 += tvv * tq2;
      sv2 += svv * td2;
    }
    float su = su2.x + su2.y, sw = sw2.x + sw2.y, sv_ = sv2.x + sv2.y;
    su  += __shfl_xor(su, 32);
    sw  += __shfl_xor(sw, 32);
    sv_ += __shfl_xor(sv_, 32);
    if (l < 16) {
      const int c = s * 16 + l;
      g[c]       = su;
      g[128 + c] = sv_;
      g[256 + c] = sw;
    }
  }

#pragma unroll
  for (int rep = 0; rep < 2; ++rep) {
    const int hp = l + rep * 64;
    const float p = (g[3 * hp] + g[3 * hp + 1] + g[3 * hp + 2]) * (1.0f / 96.0f);
    const float hs = b2f(feat16[(size_t)n * H + hp]);
    rst[(size_t)n * H + hp] = f2b(hs + p);
  }
}

// z2sim = Rs@Mss + C_CROSS*(Rc@P2) + bsim ; z2cor = Rc@Mcc + C_CROSS*(Rs@P1) + bcor.
// Transposed orientation: A = MssT/P1T rows (n in reg dim), B = Rs/Rc rows (row in
// lane dim) -> C[i][lane] has consecutive n per reg group => packed float4 stores.
__global__ __launch_bounds__(256) void finalmm_mfma(
    const unsigned short* __restrict__ Rs, const unsigned short* __restrict__ Rc,
    const unsigned short* __restrict__ MssT, const unsigned short* __restrict__ MccT,
    const unsigned short* __restrict__ P1T, const unsigned short* __restrict__ P2T,
    const float* __restrict__ bsim, const float* __restrict__ bcor,
    float* __restrict__ outp)
{
  const int t = threadIdx.x;
  const int w = t >> 6, l = t & 63, lane = l & 31, half = l >> 5;
  const int rbase = blockIdx.x * 32;
  const int orow = rbase + lane;   // output row this lane owns (B gather row)
  const int nb = w * 32;           // this wave's n-strip

  const unsigned short* rsrow = Rs + (size_t)orow * H + half * 8;
  const unsigned short* rcrow = Rc + (size_t)orow * H + half * 8;
  bf16x8 bS[8], bC[8];
#pragma unroll
  for (int s = 0; s < 8; ++s) {
    bS[s] = *(const bf16x8*)(rsrow + s * 16);
    bC[s] = *(const bf16x8*)(rcrow + s * 16);
  }

  const unsigned short* aMss = MssT + (size_t)(nb + lane) * 128 + half * 8;
  const unsigned short* aMcc = MccT + (size_t)(nb + lane) * 128 + half * 8;
  const unsigned short* aP1  = P1T  + (size_t)(nb + lane) * 128 + half * 8;
  const unsigned short* aP2  = P2T  + (size_t)(nb + lane) * 128 + half * 8;

  f32x16 a1 = {0,0,0,0,0,0,0,0,0,0,0,0,0,0,0,0};   // (Rs@Mss)^T
  f32x16 a2 = a1, a3 = a1, a4 = a1;                 // (Rc@P2)^T, (Rc@Mcc)^T, (Rs@P1)^T
#pragma unroll
  for (int s = 0; s < 8; ++s) {
    bf16x8 m1 = *(const bf16x8*)(aMss + s * 16);
    bf16x8 m2 = *(const bf16x8*)(aP2  + s * 16);
    bf16x8 m3 = *(const bf16x8*)(aMcc + s * 16);
    bf16x8 m4 = *(const bf16x8*)(aP1  + s * 16);
    a1 = __builtin_amdgcn_mfma_f32_32x32x16_bf16(m1, bS[s], a1, 0, 0, 0);
    a2 = __builtin_amdgcn_mfma_f32_32x32x16_bf16(m2, bC[s], a2, 0, 0, 0);
    a3 = __builtin_amdgcn_mfma_f32_32x32x16_bf16(m3, bC[s], a3, 0, 0, 0);
    a4 = __builtin_amdgcn_mfma_f32_32x32x16_bf16(m4, bS[s], a4, 0, 0, 0);
  }

  // C[i][lane]: n = nb + (i&3) + 8*(i>>2) + 4*half -> consecutive per 4-reg group
#pragma unroll
  for (int q = 0; q < 4; ++q) {
    const int n0 = nb + 8 * q + 4 * half;
    const float4 bsv = *(const float4*)(bsim + n0);
    const float4 bcv = *(const float4*)(bcor + n0);
    float4 v1, v2;
    v1.x = a1[4*q+0] + C_CROSS * a2[4*q+0] + bsv.x;
    v1.y = a1[4*q+1] + C_CROSS * a2[4*q+1] + bsv.y;
    v1.z = a1[4*q+2] + C_CROSS * a2[4*q+2] + bsv.z;
    v1.w = a1[4*q+3] + C_CROSS * a2[4*q+3] + bsv.w;
    v2.x = a3[4*q+0] + C_CROSS * a4[4*q+0] + bcv.x;
    v2.y = a3[4*q+1] + C_CROSS * a4[4*q+1] + bcv.y;
    v2.z = a3[4*q+2] + C_CROSS * a4[4*q+2] + bcv.z;
    v2.w = a3[4*q+3] + C_CROSS * a4[4*q+3] + bcv.w;
    *(float4*)(outp + (size_t)orow * H + n0) = v1;
    *(float4*)(outp + (size_t)NDST * H + (size_t)orow * H + n0) = v2;
  }
}

extern "C" void kernel_launch(void* const* d_in, const int* in_sizes, int n_in,
                              void* d_out, int out_size, void* d_ws, size_t ws_size,
                              hipStream_t stream) {
  const int* x    = (const int*)d_in[0];
  const int* nsim = (const int*)d_in[1];
  const int* ncor = (const int*)d_in[2];
  const void* emb0_sim = d_in[3];
  const void* emb1_sim = d_in[4];
  const void* emb0_cor = d_in[5];
  const void* emb1_cor = d_in[6];
  const void* W_in_sim  = d_in[7];
  const void* b_in_sim  = d_in[8];
  const void* W_in_cor  = d_in[9];
  const void* b_in_cor  = d_in[10];
  const void* W_out_sim = d_in[11];
  const void* b_out_sim = d_in[12];
  const void* W_out_cor = d_in[13];
  const void* b_out_cor = d_in[14];
  const void* W_sim2cor = d_in[15];
  const void* W_cor2sim = d_in[16];

  float* fbase = (float*)d_ws;
  float* P1slot = fbase;                // unused scratch slots (layout kept stable)
  float* P2slot = P1slot + H * H;
  float* p1v = P2slot + H * H;
  float* p2v = p1v + H;
  float* bsimv = p2v + H;
  float* bcorv = bsimv + H;
  int* flags = (int*)(bcorv + H);
  unsigned short* feat16_sim = (unsigned short*)(flags + 4);     // NDST*H
  unsigned short* feat16_cor = feat16_sim + (size_t)NDST * H;
  unsigned short* rst_sim    = feat16_cor + (size_t)NDST * H;
  unsigned short* rst_cor    = rst_sim + (size_t)NDST * H;
  unsigned char* feat8_sim = (unsigned char*)(rst_cor + (size_t)NDST * H);  // NSRC*H
  unsigned char* feat8_cor = feat8_sim + (size_t)NSRC * H;
  unsigned short* WT_sim = (unsigned short*)(feat8_cor + (size_t)NSRC * H);
  unsigned short* WT_cor = WT_sim + H * H;
  unsigned short* P1T  = WT_cor + H * H;
  unsigned short* P2T  = P1T + H * H;
  unsigned short* MssT = P2T + H * H;
  unsigned short* MccT = MssT + H * H;

  prep2<<<131, 256, 0, stream>>>(W_in_sim, W_in_cor, W_out_sim, W_out_cor,
                                 W_sim2cor, W_cor2sim, b_out_sim, b_out_cor,
                                 WT_sim, WT_cor, P1T, P2T, MssT, MccT, bsimv, bcorv);
  featgemm_mfma<<<dim3(NSRC / 128, 2), 256, 0, stream>>>(
      x, W_in_sim, emb0_sim, emb1_sim, emb0_cor, emb1_cor,
      WT_sim, WT_cor, b_in_sim, b_in_cor,
      feat8_sim, feat16_sim, feat8_cor, feat16_cor);
  coatt_mfma<<<dim3(NDST / 4, 2), 256, 0, stream>>>(
      feat8_sim, feat16_sim, feat8_cor, feat16_cor,
      nsim, ncor, rst_sim, rst_cor);
  finalmm_mfma<<<NDST / 32, 256, 0, stream>>>(rst_sim, rst_cor, MssT, MccT, P1T, P2T,
                                              bsimv, bcorv, (float*)d_out);
}

// Round 10
// 241.814 us; speedup vs baseline: 1.3468x; 1.0148x over previous
//
#include <hip/hip_runtime.h>
#include <hip/hip_bf16.h>

#define NSRC 65536
#define NDST 8192
#define H 128

// mixing constants: z2sim = 0.34*sim + 0.495*cor@Wcs + 0.165*sim@(Wsc@Wcs) (and sym.)
#define C_SELF 0.34f
#define C_CROSS 0.495f
#define C_DBL  0.165f

typedef float f32x16 __attribute__((ext_vector_type(16)));
typedef short bf16x8 __attribute__((ext_vector_type(8)));

static __device__ __forceinline__ float b2f(unsigned short u) {
  union { unsigned int i; float f; } v; v.i = ((unsigned int)u) << 16; return v.f;
}
static __device__ __forceinline__ unsigned short f2b(float f) {
  union { float f; unsigned int i; } v; v.f = f;
  unsigned int x = v.i;
  return (unsigned short)((x + 0x7fffu + ((x >> 16) & 1u)) >> 16);  // RNE
}
static __device__ __forceinline__ void load4bf(const unsigned short* p, float* d) {
  ushort4 u = *(const ushort4*)p;
  d[0] = b2f(u.x); d[1] = b2f(u.y); d[2] = b2f(u.z); d[3] = b2f(u.w);
}
// fp8 e4m3 x4 -> f32 (HW cvt if available; else manual incl. subnormals)
static __device__ __forceinline__ float fp8_manual(unsigned int b) {
  const unsigned e = (b >> 3) & 15u, m = b & 7u;
  union { unsigned i; float f; } v; v.i = ((e + 120u) << 23) | (m << 20);
  float f = (e == 0u) ? (float)m * 1.953125e-3f : v.f;
  return (b & 0x80u) ? -f : f;
}
static __device__ __forceinline__ void fp8x4_to_f32(int w, float* out) {
#if __has_builtin(__builtin_amdgcn_cvt_f32_fp8)
  out[0] = __builtin_amdgcn_cvt_f32_fp8(w, 0);
  out[1] = __builtin_amdgcn_cvt_f32_fp8(w, 1);
  out[2] = __builtin_amdgcn_cvt_f32_fp8(w, 2);
  out[3] = __builtin_amdgcn_cvt_f32_fp8(w, 3);
#else
  out[0] = fp8_manual((unsigned)w & 0xFFu);
  out[1] = fp8_manual(((unsigned)w >> 8) & 0xFFu);
  out[2] = fp8_manual(((unsigned)w >> 16) & 0xFFu);
  out[3] = fp8_manual(((unsigned)w >> 24) & 0xFFu);
#endif
}

// ---- DPP cross-lane (VALU pipe, not LDS) ----
template <int CTRL>
static __device__ __forceinline__ float dpp_mov(float x) {
  return __int_as_float(__builtin_amdgcn_update_dpp(
      0, __float_as_int(x), CTRL, 0xF, 0xF, true));
}
// 32-lane sum; valid in lanes 31 (half0) and 63 (half1).
static __device__ __forceinline__ float dpp_sum32_tail(float x) {
  x += dpp_mov<0x111>(x);   // row_shr:1
  x += dpp_mov<0x112>(x);   // row_shr:2
  x += dpp_mov<0x114>(x);   // row_shr:4
  x += dpp_mov<0x118>(x);   // row_shr:8
  x += dpp_mov<0x142>(x);   // row_bcast:15
  return x;
}
// 32-lane all-reduce sum: 4 DPP + 1 swizzle
static __device__ __forceinline__ float allred32_sum(float x) {
  x += dpp_mov<0xB1>(x);
  x += dpp_mov<0x4E>(x);
  x += dpp_mov<0x124>(x);
  x += dpp_mov<0x128>(x);
  x += __int_as_float(__builtin_amdgcn_ds_swizzle(__float_as_int(x), 0x401F));
  return x;
}

// dual-dtype loaders: f32flag=1 -> buffer holds float32, else bf16.
static __device__ __forceinline__ void load4any(const void* base, size_t idx, int f32flag, float* d) {
  if (f32flag) {
    float4 v = *(const float4*)((const float*)base + idx);
    d[0] = v.x; d[1] = v.y; d[2] = v.z; d[3] = v.w;
  } else {
    load4bf((const unsigned short*)base + idx, d);
  }
}
static __device__ __forceinline__ float load1any(const void* base, size_t idx, int f32flag) {
  return f32flag ? ((const float*)base)[idx] : b2f(((const unsigned short*)base)[idx]);
}

// ---- inline flag detection (per wave) ----
static __device__ __forceinline__ int detect_wf(const unsigned short* __restrict__ W) {
  const int l = threadIdx.x & 63;
  int bad = 0;
#pragma unroll
  for (int i = l; i < 128; i += 64) {
    unsigned short u = W[i];
    if (u != 0) {
      int e = (u >> 7) & 0xFF;
      if (e < 90 || e > 128) bad++;
    }
  }
#pragma unroll
  for (int d = 1; d < 64; d <<= 1) bad += __shfl_xor(bad, d);
  return (bad > 8) ? 1 : 0;
}
static __device__ __forceinline__ int detect_x64(const int* __restrict__ x) {
  const int l = threadIdx.x & 63;
  int nz = (l < 16) ? (x[2 * l + 1] != 0 ? 1 : 0) : 0;
#pragma unroll
  for (int d = 1; d < 64; d <<= 1) nz += __shfl_xor(nz, d);
  return (nz == 0) ? 1 : 0;
}

// ---- transposes to bf16: WT (W_in sim/cor) and WscT/WcsT. 512 blocks x 128. ----
__global__ __launch_bounds__(128) void transk(
    const void* __restrict__ Wsim_in, const void* __restrict__ Wcor_in,
    const void* __restrict__ Wsc, const void* __restrict__ Wcs,
    unsigned short* __restrict__ WTsim, unsigned short* __restrict__ WTcor,
    unsigned short* __restrict__ WscT, unsigned short* __restrict__ WcsT)
{
  const int wf = detect_wf((const unsigned short*)Wsim_in);
  const int bid = blockIdx.x;
  const int k = threadIdx.x;
  const int n = bid & 127;
  const void* W;
  unsigned short* WT;
  if (bid < 256) {
    W  = (bid & 128) ? Wcor_in : Wsim_in;
    WT = (bid & 128) ? WTcor : WTsim;
  } else {
    W  = (bid & 128) ? Wcs : Wsc;
    WT = (bid & 128) ? WcsT : WscT;
  }
  WT[n * 128 + k] = f2b(load1any(W, k * 128 + n, wf));
}

// ---- sgemm1: P1 = Wos@Wsc, P2 = Woc@Wcs via bf16 MFMA (finalmm pattern);
// outputs P1T/P2T (transposed bf16) + P1bf/P2bf (row-major bf16).
// Block 8: p1 = bs@Wsc, p2 = bc@Wcs (f32, k-split across 2 thread-groups). ----
__global__ __launch_bounds__(256) void sgemm1(
    const void* __restrict__ Wdet,
    const void* __restrict__ Wos, const void* __restrict__ Woc,
    const void* __restrict__ Wsc, const void* __restrict__ Wcs,
    const void* __restrict__ bs, const void* __restrict__ bc,
    const unsigned short* __restrict__ WscT, const unsigned short* __restrict__ WcsT,
    unsigned short* __restrict__ P1T, unsigned short* __restrict__ P2T,
    unsigned short* __restrict__ P1bf, unsigned short* __restrict__ P2bf,
    float* __restrict__ p1, float* __restrict__ p2)
{
  __shared__ float l1[256], l2[256];
  const int wf = detect_wf((const unsigned short*)Wdet);
  const int bid = blockIdx.x;
  const int t = threadIdx.x;

  if (bid == 8) {
    const int c = t & 127, kg = t >> 7;
    float a1 = 0.f, a2 = 0.f;
    for (int k = kg * 64; k < kg * 64 + 64; ++k) {
      a1 += load1any(bs, k, wf) * load1any(Wsc, k * 128 + c, wf);
      a2 += load1any(bc, k, wf) * load1any(Wcs, k * 128 + c, wf);
    }
    l1[t] = a1; l2[t] = a2;
    __syncthreads();
    if (kg == 0) { p1[c] = l1[c] + l1[c + 128]; p2[c] = l2[c] + l2[c + 128]; }
    return;
  }

  const bool isP2 = bid >= 4;
  const int rbase = (bid & 3) * 32;
  const void* A = isP2 ? Woc : Wos;
  const unsigned short* BT = isP2 ? WcsT : WscT;
  unsigned short* PT = isP2 ? P2T : P1T;
  unsigned short* Pb = isP2 ? P2bf : P1bf;

  const int w = t >> 6, l = t & 63, lane = l & 31, half = l >> 5;
  const int arow = rbase + lane;
  const int n = w * 32 + lane;

  bf16x8 af[8];
#pragma unroll
  for (int s = 0; s < 8; ++s) {
    float tmp[8];
    const size_t base = (size_t)arow * 128 + s * 16 + half * 8;
    load4any(A, base, wf, tmp);
    load4any(A, base + 4, wf, tmp + 4);
    union { bf16x8 v; unsigned short u[8]; } cv;
#pragma unroll
    for (int j = 0; j < 8; ++j) cv.u[j] = f2b(tmp[j]);
    af[s] = cv.v;
  }

  f32x16 acc = {0,0,0,0,0,0,0,0,0,0,0,0,0,0,0,0};
#pragma unroll
  for (int s = 0; s < 8; ++s) {
    bf16x8 bfrag = *(const bf16x8*)(BT + (size_t)n * 128 + s * 16 + half * 8);
    acc = __builtin_amdgcn_mfma_f32_32x32x16_bf16(af[s], bfrag, acc, 0, 0, 0);
  }
#pragma unroll
  for (int i = 0; i < 16; ++i) {
    const int m = (i & 3) + 8 * (i >> 2) + 4 * half;
    const int r = rbase + m;
    const unsigned short v = f2b(acc[i]);
    PT[(size_t)n * 128 + r] = v;     // transposed (for finalmm B operand)
    Pb[(size_t)r * 128 + n] = v;     // row-major (for sgemm2 A operand)
  }
}

// ---- sgemm2: MssT = (C_SELF*Wos + C_DBL*(P1@Wcs))^T, MccT sym.;
// block 8: fused bias vectors. ----
__global__ __launch_bounds__(256) void sgemm2(
    const void* __restrict__ Wdet,
    const void* __restrict__ Wos, const void* __restrict__ Woc,
    const void* __restrict__ Wsc, const void* __restrict__ Wcs,
    const void* __restrict__ bs, const void* __restrict__ bc,
    const unsigned short* __restrict__ WscT, const unsigned short* __restrict__ WcsT,
    const unsigned short* __restrict__ P1bf, const unsigned short* __restrict__ P2bf,
    const float* __restrict__ p1, const float* __restrict__ p2,
    unsigned short* __restrict__ MssT, unsigned short* __restrict__ MccT,
    float* __restrict__ bsim, float* __restrict__ bcor)
{
  __shared__ float l1[256], l2[256];
  const int wf = detect_wf((const unsigned short*)Wdet);
  const int bid = blockIdx.x;
  const int t = threadIdx.x;

  if (bid == 8) {
    const int c = t & 127, kg = t >> 7;
    float a3 = 0.f, a4 = 0.f;
    for (int k = kg * 64; k < kg * 64 + 64; ++k) {
      a3 += p1[k] * load1any(Wcs, k * 128 + c, wf);
      a4 += p2[k] * load1any(Wsc, k * 128 + c, wf);
    }
    l1[t] = a3; l2[t] = a4;
    __syncthreads();
    if (kg == 0) {
      bsim[c] = C_SELF * load1any(bs, c, wf) + C_CROSS * p2[c] + C_DBL * (l1[c] + l1[c + 128]);
      bcor[c] = C_SELF * load1any(bc, c, wf) + C_CROSS * p1[c] + C_DBL * (l2[c] + l2[c + 128]);
    }
    return;
  }

  const bool isMcc = bid >= 4;
  const int rbase = (bid & 3) * 32;
  const unsigned short* A = isMcc ? P2bf : P1bf;   // P2@Wsc / P1@Wcs
  const unsigned short* BT = isMcc ? WscT : WcsT;
  const void* Wself = isMcc ? Woc : Wos;
  unsigned short* out = isMcc ? MccT : MssT;

  const int w = t >> 6, l = t & 63, lane = l & 31, half = l >> 5;
  const int arow = rbase + lane;
  const int n = w * 32 + lane;

  bf16x8 af[8];
#pragma unroll
  for (int s = 0; s < 8; ++s)
    af[s] = *(const bf16x8*)(A + (size_t)arow * 128 + s * 16 + half * 8);

  f32x16 acc = {0,0,0,0,0,0,0,0,0,0,0,0,0,0,0,0};
#pragma unroll
  for (int s = 0; s < 8; ++s) {
    bf16x8 bfrag = *(const bf16x8*)(BT + (size_t)n * 128 + s * 16 + half * 8);
    acc = __builtin_amdgcn_mfma_f32_32x32x16_bf16(af[s], bfrag, acc, 0, 0, 0);
  }
#pragma unroll
  for (int i = 0; i < 16; ++i) {
    const int m = (i & 3) + 8 * (i >> 2) + 4 * half;
    const int r = rbase + m;
    out[(size_t)n * 128 + r] =
        f2b(C_SELF * load1any(Wself, (size_t)r * 128 + n, wf) + C_DBL * acc[i]);
  }
}

// feat = [emb0[x0]|emb1[x1]] @ W + b via bf16 MFMA. Both modes in one launch
// (blockIdx.y selects sim/cor). Block = 4 waves x 32 rows each; each WAVE covers
// all 128 cols in 4 strips, reusing its A fragments (gather+cvt amortized 4x).
// NOTE: do NOT split strips across blocks — emb1 (38 MB) exceeds L2, re-gather
// misses HBM twice (round-5 regression).
__global__ __launch_bounds__(256) void featgemm_mfma(
    const int* __restrict__ x,
    const void* __restrict__ Wdet,
    const void* __restrict__ emb0s, const void* __restrict__ emb1s,
    const void* __restrict__ emb0c, const void* __restrict__ emb1c,
    const unsigned short* __restrict__ WTs, const unsigned short* __restrict__ WTc,
    const void* __restrict__ bvs, const void* __restrict__ bvc,
    unsigned char* __restrict__ f8s, unsigned short* __restrict__ f16s,
    unsigned char* __restrict__ f8c, unsigned short* __restrict__ f16c)
{
  const int wf  = detect_wf((const unsigned short*)Wdet);
  const int x64 = detect_x64(x);
  const int mode = blockIdx.y;
  const void* emb0 = mode ? emb0c : emb0s;
  const void* emb1 = mode ? emb1c : emb1s;
  const unsigned short* WT = mode ? WTc : WTs;
  const void* bvec = mode ? bvc : bvs;
  unsigned char*  feat8  = mode ? f8c  : f8s;
  unsigned short* feat16 = mode ? f16c : f16s;

  const int t = threadIdx.x;
  const int w = t >> 6, l = t & 63, lane = l & 31, half = l >> 5;
  const int rbase = blockIdx.x * 128 + w * 32;
  const int r = rbase + lane;            // A row this lane gathers

  int x0, x1;
  if (x64) { x0 = x[r * 4]; x1 = x[r * 4 + 2]; }
  else     { x0 = x[r * 2]; x1 = x[r * 2 + 1]; }

  bf16x8 afrag[8];
#pragma unroll
  for (int s = 0; s < 8; ++s) {
    float tmp[8];
    if (s < 2) {
      const size_t base = (size_t)x0 * 32 + s * 16 + half * 8;
      load4any(emb0, base, wf, tmp);
      load4any(emb0, base + 4, wf, tmp + 4);
    } else {
      const size_t base = (size_t)x1 * 96 + (s * 16 - 32) + half * 8;
      load4any(emb1, base, wf, tmp);
      load4any(emb1, base + 4, wf, tmp + 4);
    }
    union { bf16x8 v; unsigned short u[8]; } cv;
#pragma unroll
    for (int j = 0; j < 8; ++j) cv.u[j] = f2b(tmp[j]);
    afrag[s] = cv.v;
  }

  const bool do16 = (rbase < NDST);
#pragma unroll
  for (int strip = 0; strip < 4; ++strip) {
    const int n = strip * 32 + lane;
    const unsigned short* wtrow = WT + (size_t)n * 128 + half * 8;
    f32x16 acc = {0,0,0,0,0,0,0,0,0,0,0,0,0,0,0,0};
#pragma unroll
    for (int s = 0; s < 8; ++s) {
      bf16x8 bfrag = *(const bf16x8*)(wtrow + s * 16);
      acc = __builtin_amdgcn_mfma_f32_32x32x16_bf16(afrag[s], bfrag, acc, 0, 0, 0);
    }
    const float bias_n = load1any(bvec, n, wf);
#pragma unroll
    for (int i = 0; i < 16; ++i) {
      const int m = (i & 3) + 8 * (i >> 2) + 4 * half;
      const int row = rbase + m;
      const float val = acc[i] + bias_n;
      const int p8 = __builtin_amdgcn_cvt_pk_fp8_f32(val, val, 0, false);
      feat8[(size_t)row * H + n] = (unsigned char)(p8 & 0xFF);
      if (do16) feat16[(size_t)row * H + n] = f2b(val);
    }
  }
}

// Collapsed co-attention pool, one WAVE per node; both modes in one launch.
// fp8 gather + fp8 MFMA + DPP reductions; pooled sums via identity-B transpose-MFMA
// (scalar accumulation — float2 variant measured slower). allred32-based row
// denominators (LDS-staged variant produced NaN in round 9 — keep allred32).
// Plain __launch_bounds__(256): (256,8) caps VGPR at 32 -> 254MB scratch spill
// (round 7). Never starve this kernel.
__global__ __launch_bounds__(256) void coatt_mfma(
    const unsigned char* __restrict__ f8s, const unsigned short* __restrict__ f16s,
    const unsigned char* __restrict__ f8c, const unsigned short* __restrict__ f16c,
    const int* __restrict__ nsim, const int* __restrict__ ncor,
    unsigned short* __restrict__ rsts, unsigned short* __restrict__ rstc)
{
  const int mode = blockIdx.y;
  const unsigned char*  feat8  = mode ? f8c  : f8s;
  const unsigned short* feat16 = mode ? f16c : f16s;
  const int* idxD = mode ? nsim : ncor;   // 'sim': D=neigh_cor; 'cor': D=neigh_sim
  const int* idxQ = mode ? ncor : nsim;
  unsigned short* rst = mode ? rstc : rsts;

  __shared__ float gbuf[4][448];   // per wave: g[384] | sv[32] | tv[32]
  const int t = threadIdx.x;
  const int w = t >> 6;            // wave in block
  const int l = t & 63;            // lane
  const int r = l & 31;            // row index within D/Q tiles
  const int half = l >> 5;
  const int n = blockIdx.x * 4 + w;

  float* g   = gbuf[w];
  float* svb = gbuf[w] + 384;
  float* tvb = gbuf[w] + 416;

  const int gD = idxD[n * 32 + r];
  const int gQ = idxQ[n * 32 + r];
  const unsigned char* drow = feat8 + (size_t)gD * H + half * 8;
  const unsigned char* qrow = feat8 + (size_t)gQ * H + half * 8;

  long dfrag[8], qfrag[8];
#pragma unroll
  for (int s = 0; s < 8; ++s) {
    dfrag[s] = *(const long*)(drow + s * 16);
    qfrag[s] = *(const long*)(qrow + s * 16);
  }

  f32x16 acc = {0,0,0,0,0,0,0,0,0,0,0,0,0,0,0,0};
#pragma unroll
  for (int s = 0; s < 8; ++s)
    acc = __builtin_amdgcn_mfma_f32_32x32x16_fp8_fp8(dfrag[s], qfrag[s], acc, 0, 0, 0);
  // L[m][k]: col k = l&31, row m = (reg&3) + 8*(reg>>2) + 4*half

  // exp(L) once, shared by AC and AS
  float ex[16], rrcp[16];
#pragma unroll
  for (int i = 0; i < 16; ++i) ex[i] = __expf(acc[i]);
  // row softmax denominators (over k = 32 lanes of this half)
#pragma unroll
  for (int i = 0; i < 16; ++i) rrcp[i] = 1.0f / allred32_sum(ex[i]);
  // col denominators (over m = 16 regs in-lane + partner lane l^32)
  float csum = 0.f;
#pragma unroll
  for (int i = 0; i < 16; ++i) csum += ex[i];
  csum += __shfl_xor(csum, 32);
  const float crcp = 1.0f / csum;

  // sv[m] = sum_k AS[k,m]: DPP tail sums, staged to LDS
  float svt[16];
#pragma unroll
  for (int i = 0; i < 16; ++i) svt[i] = dpp_sum32_tail(ex[i] * crcp);
  if (r == 31) {
    *(float4*)(svb + 4 * half)      = make_float4(svt[0],  svt[1],  svt[2],  svt[3]);
    *(float4*)(svb + 8 + 4 * half)  = make_float4(svt[4],  svt[5],  svt[6],  svt[7]);
    *(float4*)(svb + 16 + 4 * half) = make_float4(svt[8],  svt[9],  svt[10], svt[11]);
    *(float4*)(svb + 24 + 4 * half) = make_float4(svt[12], svt[13], svt[14], svt[15]);
  }
  float sv16[16];
#pragma unroll
  for (int q = 0; q < 4; ++q) {
    float4 v = *(const float4*)(svb + q * 8 + 4 * half);
    sv16[q * 4] = v.x; sv16[q * 4 + 1] = v.y; sv16[q * 4 + 2] = v.z; sv16[q * 4 + 3] = v.w;
  }
  float tvp = 0.f;
#pragma unroll
  for (int i = 0; i < 16; ++i) tvp += sv16[i] * ex[i] * rrcp[i];
  const float tv = tvp + __shfl_xor(tvp, 32);

  // stage tv to LDS so each lane can fetch tv[rowmap(i)] (same pattern as sv16)
  if (l < 32) tvb[l] = tv;
  float tv16[16];
#pragma unroll
  for (int q = 0; q < 4; ++q) {
    float4 vv = *(const float4*)(tvb + q * 8 + 4 * half);
    tv16[q * 4] = vv.x; tv16[q * 4 + 1] = vv.y; tv16[q * 4 + 2] = vv.z; tv16[q * 4 + 3] = vv.w;
  }

  // ---- pooled: g = [u | v | w] via transpose-MFMA ----
  // B[k][c] = delta(k, c&15): fp8(1.0) = 0x38 at byte (l&15)-half*8 if in [0,8)
  const int bpos = (l & 15) - half * 8;
  const long b_ident = (bpos >= 0 && bpos < 8) ? (0x38L << (8 * bpos)) : 0L;
  const f32x16 zf = {0,0,0,0,0,0,0,0,0,0,0,0,0,0,0,0};

#pragma unroll
  for (int s = 0; s < 8; ++s) {
    // td[i] = D[rowmap(i)][s*16 + (l&15)], tq[i] = Q[rowmap(i)][s*16 + (l&15)]
    f32x16 td = __builtin_amdgcn_mfma_f32_32x32x16_fp8_fp8(dfrag[s], b_ident, zf, 0, 0, 0);
    f32x16 tq = __builtin_amdgcn_mfma_f32_32x32x16_fp8_fp8(qfrag[s], b_ident, zf, 0, 0, 0);
    float su = 0.f, sw = 0.f, sv_ = 0.f;
#pragma unroll
    for (int i = 0; i < 16; ++i) {
      su  += tq[i];
      sw  += tv16[i] * tq[i];
      sv_ += sv16[i] * td[i];
    }
    su  += __shfl_xor(su, 32);
    sw  += __shfl_xor(sw, 32);
    sv_ += __shfl_xor(sv_, 32);
    if (l < 16) {
      const int c = s * 16 + l;
      g[c]       = su;
      g[128 + c] = sv_;
      g[256 + c] = sw;
    }
  }

#pragma unroll
  for (int rep = 0; rep < 2; ++rep) {
    const int hp = l + rep * 64;
    const float p = (g[3 * hp] + g[3 * hp + 1] + g[3 * hp + 2]) * (1.0f / 96.0f);
    const float hs = b2f(feat16[(size_t)n * H + hp]);
    rst[(size_t)n * H + hp] = f2b(hs + p);
  }
}

// z2sim = Rs@Mss + C_CROSS*(Rc@P2) + bsim ; z2cor = Rc@Mcc + C_CROSS*(Rs@P1) + bcor
// MFMA version: B operands are transposed bf16 matrices. Block = 32 rows, 4 strip-waves.
__global__ __launch_bounds__(256) void finalmm_mfma(
    const unsigned short* __restrict__ Rs, const unsigned short* __restrict__ Rc,
    const unsigned short* __restrict__ MssT, const unsigned short* __restrict__ MccT,
    const unsigned short* __restrict__ P1T, const unsigned short* __restrict__ P2T,
    const float* __restrict__ bsim, const float* __restrict__ bcor,
    float* __restrict__ outp)
{
  const int t = threadIdx.x;
  const int w = t >> 6, l = t & 63, lane = l & 31, half = l >> 5;
  const int rbase = blockIdx.x * 32;
  const int arow = rbase + lane;
  const int n = w * 32 + lane;     // output column this lane owns

  const unsigned short* rsrow = Rs + (size_t)arow * H + half * 8;
  const unsigned short* rcrow = Rc + (size_t)arow * H + half * 8;
  bf16x8 aS[8], aC[8];
#pragma unroll
  for (int s = 0; s < 8; ++s) {
    aS[s] = *(const bf16x8*)(rsrow + s * 16);
    aC[s] = *(const bf16x8*)(rcrow + s * 16);
  }

  const unsigned short* bMss = MssT + (size_t)n * 128 + half * 8;
  const unsigned short* bMcc = MccT + (size_t)n * 128 + half * 8;
  const unsigned short* bP1  = P1T  + (size_t)n * 128 + half * 8;
  const unsigned short* bP2  = P2T  + (size_t)n * 128 + half * 8;

  f32x16 a1 = {0,0,0,0,0,0,0,0,0,0,0,0,0,0,0,0};   // Rs@Mss
  f32x16 a2 = a1, a3 = a1, a4 = a1;                 // Rc@P2, Rc@Mcc, Rs@P1
#pragma unroll
  for (int s = 0; s < 8; ++s) {
    bf16x8 b1 = *(const bf16x8*)(bMss + s * 16);
    bf16x8 b2 = *(const bf16x8*)(bP2  + s * 16);
    bf16x8 b3 = *(const bf16x8*)(bMcc + s * 16);
    bf16x8 b4 = *(const bf16x8*)(bP1  + s * 16);
    a1 = __builtin_amdgcn_mfma_f32_32x32x16_bf16(aS[s], b1, a1, 0, 0, 0);
    a2 = __builtin_amdgcn_mfma_f32_32x32x16_bf16(aC[s], b2, a2, 0, 0, 0);
    a3 = __builtin_amdgcn_mfma_f32_32x32x16_bf16(aC[s], b3, a3, 0, 0, 0);
    a4 = __builtin_amdgcn_mfma_f32_32x32x16_bf16(aS[s], b4, a4, 0, 0, 0);
  }

  const float bsv = bsim[n], bcv = bcor[n];
#pragma unroll
  for (int i = 0; i < 16; ++i) {
    const int m = (i & 3) + 8 * (i >> 2) + 4 * half;
    const int row = rbase + m;
    outp[(size_t)row * H + n] = a1[i] + C_CROSS * a2[i] + bsv;
    outp[(size_t)NDST * H + (size_t)row * H + n] = a3[i] + C_CROSS * a4[i] + bcv;
  }
}

extern "C" void kernel_launch(void* const* d_in, const int* in_sizes, int n_in,
                              void* d_out, int out_size, void* d_ws, size_t ws_size,
                              hipStream_t stream) {
  const int* x    = (const int*)d_in[0];
  const int* nsim = (const int*)d_in[1];
  const int* ncor = (const int*)d_in[2];
  const void* emb0_sim = d_in[3];
  const void* emb1_sim = d_in[4];
  const void* emb0_cor = d_in[5];
  const void* emb1_cor = d_in[6];
  const void* W_in_sim  = d_in[7];
  const void* b_in_sim  = d_in[8];
  const void* W_in_cor  = d_in[9];
  const void* b_in_cor  = d_in[10];
  const void* W_out_sim = d_in[11];
  const void* b_out_sim = d_in[12];
  const void* W_out_cor = d_in[13];
  const void* b_out_cor = d_in[14];
  const void* W_sim2cor = d_in[15];
  const void* W_cor2sim = d_in[16];

  // layout (old P1/P2 f32 slots recycled as bf16 scratch)
  float* fbase = (float*)d_ws;
  float* P1slot = fbase;                // 128*128 f32 slot -> WscT|WcsT (bf16)
  float* P2slot = P1slot + H * H;       // 128*128 f32 slot -> P1bf|P2bf (bf16)
  float* p1v = P2slot + H * H;          // 128 f32 each
  float* p2v = p1v + H;
  float* bsimv = p2v + H;
  float* bcorv = bsimv + H;
  int* flags = (int*)(bcorv + H);       // 4 ints (unused)
  unsigned short* feat16_sim = (unsigned short*)(flags + 4);     // NDST*H
  unsigned short* feat16_cor = feat16_sim + (size_t)NDST * H;
  unsigned short* rst_sim    = feat16_cor + (size_t)NDST * H;    // NDST*H
  unsigned short* rst_cor    = rst_sim + (size_t)NDST * H;
  unsigned char* feat8_sim = (unsigned char*)(rst_cor + (size_t)NDST * H);  // NSRC*H bytes
  unsigned char* feat8_cor = feat8_sim + (size_t)NSRC * H;
  unsigned short* WT_sim = (unsigned short*)(feat8_cor + (size_t)NSRC * H); // 128*128 bf16 each
  unsigned short* WT_cor = WT_sim + H * H;
  unsigned short* P1T  = WT_cor + H * H;
  unsigned short* P2T  = P1T + H * H;
  unsigned short* MssT = P2T + H * H;
  unsigned short* MccT = MssT + H * H;
  unsigned short* WscT = (unsigned short*)P1slot;
  unsigned short* WcsT = WscT + H * H;
  unsigned short* P1bf = (unsigned short*)P2slot;
  unsigned short* P2bf = P1bf + H * H;

  transk<<<512, 128, 0, stream>>>(W_in_sim, W_in_cor, W_sim2cor, W_cor2sim,
                                  WT_sim, WT_cor, WscT, WcsT);
  sgemm1<<<9, 256, 0, stream>>>(W_in_sim, W_out_sim, W_out_cor, W_sim2cor, W_cor2sim,
                                b_out_sim, b_out_cor, WscT, WcsT,
                                P1T, P2T, P1bf, P2bf, p1v, p2v);
  sgemm2<<<9, 256, 0, stream>>>(W_in_sim, W_out_sim, W_out_cor, W_sim2cor, W_cor2sim,
                                b_out_sim, b_out_cor, WscT, WcsT,
                                P1bf, P2bf, p1v, p2v, MssT, MccT, bsimv, bcorv);
  featgemm_mfma<<<dim3(NSRC / 128, 2), 256, 0, stream>>>(
      x, W_in_sim, emb0_sim, emb1_sim, emb0_cor, emb1_cor,
      WT_sim, WT_cor, b_in_sim, b_in_cor,
      feat8_sim, feat16_sim, feat8_cor, feat16_cor);
  coatt_mfma<<<dim3(NDST / 4, 2), 256, 0, stream>>>(
      feat8_sim, feat16_sim, feat8_cor, feat16_cor,
      nsim, ncor, rst_sim, rst_cor);
  finalmm_mfma<<<NDST / 32, 256, 0, stream>>>(rst_sim, rst_cor, MssT, MccT, P1T, P2T,
                                              bsimv, bcorv, (float*)d_out);
}